// Round 1
// 2104.806 us; speedup vs baseline: 1.0802x; 1.0802x over previous
//
#include <hip/hip_runtime.h>
#include <math.h>

#define TT 32
#define NB 32
#define DOBS 64
#define HID 512
#define HEADS 4
#define MEM 128
#define NACT 16
#define XID 3607
#define G3 1536

__device__ __forceinline__ float sigm(float x){ return 1.0f/(1.0f+__expf(-x)); }
__device__ __forceinline__ float splus(float x){ return fmaxf(x,0.f) + log1pf(__expf(-fabsf(x))); }

// ---------------- transpose (32x32 tiles via LDS) ----------------
__global__ __launch_bounds__(256) void k_transpose(const float* __restrict__ src,
                                                   float* __restrict__ dst, int R, int C)
{
    __shared__ float tile[32][33];
    int r0 = blockIdx.x*32, c0 = blockIdx.y*32;
    int tx = threadIdx.x, ty = threadIdx.y;
    #pragma unroll
    for (int yy = 0; yy < 32; yy += 8) {
        int r = r0 + ty + yy, c = c0 + tx;
        if (r < R && c < C) tile[ty+yy][tx] = src[(size_t)r*C + c];
    }
    __syncthreads();
    #pragma unroll
    for (int yy = 0; yy < 32; yy += 8) {
        int c = c0 + ty + yy, r = r0 + tx;
        if (r < R && c < C) dst[(size_t)c*R + r] = tile[tx][ty+yy];
    }
}

// ---------------- GRU: one block per batch chain ----------------
__global__ __launch_bounds__(512) void k_gru(
    const float* __restrict__ x,
    const float* __restrict__ wihT,   // [64][1536]
    const float* __restrict__ whhT,   // [512][1536]
    const float* __restrict__ b_ih,
    const float* __restrict__ b_hh,
    float* __restrict__ h_all)        // [T*N][512]
{
    const int n = blockIdx.x;
    const int tid = threadIdx.x;
    __shared__ float hS[512];
    __shared__ float xS[64];
    __shared__ float grS[512], gzS[512], giN[512], ghN[512];
    hS[tid] = 0.f;

    for (int t = 0; t < TT; ++t) {
        if (tid < 64) xS[tid] = x[((size_t)t*NB + n)*DOBS + tid];
        __syncthreads();
        if (tid < 384) {
            const int r0 = tid*4;
            float4 aI = *(const float4*)(b_ih + r0);
            float4 aH = *(const float4*)(b_hh + r0);
            #pragma unroll 4
            for (int k = 0; k < DOBS; ++k) {
                float xv = xS[k];
                float4 w = *(const float4*)(wihT + (size_t)k*G3 + r0);
                aI.x += w.x*xv; aI.y += w.y*xv; aI.z += w.z*xv; aI.w += w.w*xv;
            }
            #pragma unroll 4
            for (int k = 0; k < HID; ++k) {
                float hv = hS[k];
                float4 w = *(const float4*)(whhT + (size_t)k*G3 + r0);
                aH.x += w.x*hv; aH.y += w.y*hv; aH.z += w.z*hv; aH.w += w.w*hv;
            }
            if (r0 < 512) {
                grS[r0+0]=aI.x+aH.x; grS[r0+1]=aI.y+aH.y; grS[r0+2]=aI.z+aH.z; grS[r0+3]=aI.w+aH.w;
            } else if (r0 < 1024) {
                int b = r0-512;
                gzS[b+0]=aI.x+aH.x; gzS[b+1]=aI.y+aH.y; gzS[b+2]=aI.z+aH.z; gzS[b+3]=aI.w+aH.w;
            } else {
                int b = r0-1024;
                giN[b+0]=aI.x; giN[b+1]=aI.y; giN[b+2]=aI.z; giN[b+3]=aI.w;
                ghN[b+0]=aH.x; ghN[b+1]=aH.y; ghN[b+2]=aH.z; ghN[b+3]=aH.w;
            }
        }
        __syncthreads();
        {
            const int d = tid;
            float rg = sigm(grS[d]);
            float zg = sigm(gzS[d]);
            float ng = tanhf(giN[d] + rg*ghN[d]);
            float hn = (1.f-zg)*ng + zg*hS[d];
            hS[d] = hn;
            h_all[((size_t)t*NB + n)*HID + d] = hn;
        }
        __syncthreads();
    }
}

// ---------------- xi = relu(h_all) @ Wf^T + bf  (128x64 tiles, 8x4 acc) ----------------
__global__ __launch_bounds__(256) void k_xi(
    const float* __restrict__ h_all,
    const float* __restrict__ Wf,
    const float* __restrict__ bf,
    float* __restrict__ xi_all)
{
    __shared__ float As[16][132];
    __shared__ float Bs[16][68];
    const int jt = blockIdx.x * 64;
    const int it = blockIdx.y * 128;
    const int tid = threadIdx.x;
    const int lc = tid & 15, lr = tid >> 4;
    const int tx = tid & 15, ty = tid >> 4;
    float acc[8][4] = {};

    for (int k0 = 0; k0 < HID; k0 += 16) {
        #pragma unroll
        for (int s = 0; s < 8; ++s) {
            int i = lr*8 + s;
            As[lc][i] = fmaxf(h_all[(size_t)(it + i)*HID + k0 + lc], 0.f);
        }
        #pragma unroll
        for (int s = 0; s < 4; ++s) {
            int j = lr*4 + s;
            Bs[lc][j] = (jt + j < XID) ? Wf[(size_t)(jt + j)*HID + k0 + lc] : 0.f;
        }
        __syncthreads();
        #pragma unroll
        for (int k = 0; k < 16; ++k) {
            float a[8], b[4];
            #pragma unroll
            for (int u = 0; u < 8; ++u) a[u] = As[k][ty*8+u];
            #pragma unroll
            for (int v = 0; v < 4; ++v) b[v] = Bs[k][tx*4+v];
            #pragma unroll
            for (int u = 0; u < 8; ++u)
                #pragma unroll
                for (int v = 0; v < 4; ++v) acc[u][v] += a[u]*b[v];
        }
        __syncthreads();
    }
    #pragma unroll
    for (int u = 0; u < 8; ++u)
        #pragma unroll
        for (int v = 0; v < 4; ++v) {
            int i = it + ty*8 + u, j = jt + tx*4 + v;
            if (j < XID) xi_all[(size_t)i*XID + j] = acc[u][v] + bf[j];
        }
}

// ---------------- critic head ----------------
__global__ __launch_bounds__(64) void k_val(
    const float* __restrict__ h_all, const float* __restrict__ Wc,
    const float* __restrict__ bc, float* __restrict__ out)
{
    const int row = blockIdx.x;
    const int lane = threadIdx.x;
    float acc = 0.f;
    for (int d = lane; d < HID; d += 64) acc += h_all[(size_t)row*HID + d]*Wc[d];
    for (int off = 32; off; off >>= 1) acc += __shfl_down(acc, off);
    if (lane == 0) out[(size_t)row*17 + 16] = acc + bc[0];
}

// ---------------- memory recurrence: 1024 threads, M in registers, L in LDS ----------------
#define LPAD 132
#define SROW 544
#define DYN_FLOATS (128*LPAD + 16*SROW)

__global__ __launch_bounds__(1024) void k_mem(
    const float* __restrict__ xi_all, // [1024][3607]
    const float* __restrict__ Wa,     // [16][512]
    const float* __restrict__ ba,     // [16]
    float* __restrict__ out)          // [1024][17]
{
    extern __shared__ __align__(16) float dynS[];
    float* Lm  = dynS;                // [128][LPAD]
    float* scr = dynS + 128*LPAD;     // [16][SROW]

    const int n = blockIdx.x;
    const int tid = threadIdx.x;
    const int lane = tid & 63;
    const int wv = tid >> 6;          // 0..15
    const int m8 = tid >> 3;          // row 0..127
    const int q8 = tid & 7;           // col-group 0..7 (64 cols each)

    __shared__ __align__(16) float Kr_S[4][4][132];
    __shared__ __align__(16) float kw_S[4][132], e_S[4][132], v_S[4][132];
    __shared__ __align__(16) float r_S[520];
    __shared__ float wr_S[4][132];
    __shared__ float dotK_S[4][132], fwd_S[4][132], bwd_S[4][132];
    __shared__ float u_S[128], ww_S[128], p_S[128], cw_S[128], srt_S[128], aS_S[128];
    __shared__ float Mn2_S[128], dw_S[128], nrm_S[128];
    __shared__ int   rk_S[128];
    __shared__ float wred[16][6];
    __shared__ float scal_S[8];                 // 0=bw 1=ga 2=gw 3=kwn
    __shared__ float PiRaw[12];
    __shared__ float Pi_S[4][3], Br_S[4], KrN_S[4], F_S[4];
    __shared__ float ba_S[16], logit_S[16];

    // M[m8][q8*64 + 4c + j], c<16 : 16 float4 per thread (64 VGPRs)
    float4 Mreg[16];
    #pragma unroll
    for (int i = 0; i < 16; ++i) Mreg[i] = make_float4(0.f,0.f,0.f,0.f);

    for (int i = tid; i < 128*LPAD; i += 1024) Lm[i] = 0.f;
    if (tid < 16) ba_S[tid] = ba[tid];
    if (tid < 128) { u_S[tid]=0.f; ww_S[tid]=0.f; p_S[tid]=0.f; }
    if (tid < 512) wr_S[tid>>7][tid&127] = 0.f;

    // extra-scalar mapping (23 scalars on threads 1000..1022)
    const bool hasEx = (tid >= 1000 && tid < 1023);
    int exIdx = 0;
    if (tid >= 1000 && tid < 1004)      exIdx = 2048 + (tid - 1000);  // Br
    else if (tid == 1004)               exIdx = 2564;                 // bw
    else if (tid >= 1005 && tid < 1023) exIdx = 3589 + (tid - 1005);  // F(4),ga,gw,Pi(12)

    // initial prefetch (t = 0)
    const float* xi0 = xi_all + (size_t)n*XID;
    float pKrA = xi0[tid];
    float pKrB = xi0[1024 + tid];
    float pkw = 0.f, pv = 0.f, pe = 0.f;
    if (tid < 512) { pkw = xi0[2052 + tid]; pv = xi0[3077 + tid]; }
    else           { pe  = xi0[2565 + (tid - 512)]; }
    float pex = hasEx ? xi0[exIdx] : 0.f;
    __syncthreads();   // b0: LDS init done

    for (int t = 0; t < TT; ++t) {
        float scv = 0.f, ev2 = 0.f;

        // ---- P0: reg -> LDS with activations; norm partials; issue prefetch(t+1) ----
        Kr_S[tid>>9][(tid>>7)&3][tid&127]       = pKrA;
        Kr_S[2 + (tid>>9)][(tid>>7)&3][tid&127] = pKrB;
        if (tid < 512) { kw_S[tid>>7][tid&127] = pkw; v_S[tid>>7][tid&127] = pv; }
        else { int s2 = tid - 512; e_S[s2>>7][s2&127] = sigm(pe); }
        if (hasEx) {
            if (tid < 1004)      Br_S[tid-1000] = splus(pex);
            else if (tid==1004)  scal_S[0] = splus(pex);
            else if (tid < 1009) F_S[tid-1005] = sigm(pex);
            else if (tid==1009)  scal_S[1] = sigm(pex);
            else if (tid==1010)  scal_S[2] = sigm(pex);
            else                 PiRaw[tid-1011] = pex;
        }
        {
            float sA = pKrA*pKrA, sB = pKrB*pKrB, sK = pkw*pkw;
            #pragma unroll
            for (int mk = 1; mk < 64; mk <<= 1) {
                sA += __shfl_xor(sA,mk); sB += __shfl_xor(sB,mk); sK += __shfl_xor(sK,mk);
            }
            if (lane == 0) { wred[wv][0]=sA; wred[wv][1]=sB; wred[wv][2]=sK; }
        }
        {   // prefetch next step
            int tn = (t+1 < TT) ? (t+1) : t;
            const float* xin = xi_all + (size_t)(tn*NB + n)*XID;
            pKrA = xin[tid]; pKrB = xin[1024 + tid];
            if (tid < 512) { pkw = xin[2052 + tid]; pv = xin[3077 + tid]; }
            else           { pe  = xin[2565 + (tid - 512)]; }
            if (hasEx) pex = xin[exIdx];
        }
        __syncthreads();   // b1

        // ---- A: finalize norms; usage update (old wr/ww); cw raw dots on OLD M ----
        if (tid < 4) {
            float s = 0.f;
            #pragma unroll
            for (int w = 0; w < 8; ++w) s += wred[(tid&1)*8 + w][tid>>1];
            KrN_S[tid] = sqrtf(s);
        } else if (tid == 4) {
            float s = 0.f;
            #pragma unroll
            for (int w = 0; w < 8; ++w) s += wred[w][2];
            scal_S[3] = sqrtf(s);
        }
        if (tid < 128) {
            float psi = (1.f - F_S[0]*wr_S[0][tid]) * (1.f - F_S[1]*wr_S[1][tid])
                      * (1.f - F_S[2]*wr_S[2][tid]) * (1.f - F_S[3]*wr_S[3][tid]);
            float uu = u_S[tid], w = ww_S[tid];
            u_S[tid] = (uu + w - uu*w)*psi;
        }
        {
            const float* kwp = &kw_S[q8>>1][(q8&1)*64];
            float nrmO = 0.f, dw = 0.f;
            #pragma unroll
            for (int c = 0; c < 16; ++c) {
                float4 x = Mreg[c];
                float4 kk = *(const float4*)(kwp + 4*c);
                nrmO += x.x*x.x + x.y*x.y + x.z*x.z + x.w*x.w;
                dw   += x.x*kk.x + x.y*kk.y + x.z*kk.z + x.w*kk.w;
            }
            dw   += __shfl_xor(dw,1);   dw   += __shfl_xor(dw,2);   dw   += __shfl_xor(dw,4);
            nrmO += __shfl_xor(nrmO,1); nrmO += __shfl_xor(nrmO,2); nrmO += __shfl_xor(nrmO,4);
            if (q8 == 0) { dw_S[m8] = dw; nrm_S[m8] = nrmO; }
        }
        __syncthreads();   // b2

        // ---- B: cw scores; parallel rank; cwmax partial; Pi softmax ----
        {
            float um = u_S[m8];
            int rk = 0;
            #pragma unroll
            for (int jj = 0; jj < 16; ++jj) {
                int j = jj*8 + q8;
                float uj = u_S[j];
                rk += (uj < um || (uj == um && j < m8)) ? 1 : 0;
            }
            rk += __shfl_xor(rk,1); rk += __shfl_xor(rk,2); rk += __shfl_xor(rk,4);
            if (q8 == 0) { rk_S[m8] = rk; srt_S[rk] = um; }
        }
        if (tid < 128) {
            float cwv = scal_S[0]*dw_S[tid]/(sqrtf(nrm_S[tid])*scal_S[3] + 1e-8f);
            cw_S[tid] = cwv;
            float mx = cwv;
            #pragma unroll
            for (int mk = 1; mk < 64; mk <<= 1) mx = fmaxf(mx, __shfl_xor(mx,mk));
            if (lane == 0) wred[wv][0] = mx;
        } else if (tid >= 136 && tid < 140) {
            int h = tid - 136;
            float p0 = PiRaw[3*h], p1 = PiRaw[3*h+1], p2 = PiRaw[3*h+2];
            float mx = fmaxf(p0, fmaxf(p1, p2));
            float e0=__expf(p0-mx), e1=__expf(p1-mx), e2=__expf(p2-mx);
            float s = e0+e1+e2;
            Pi_S[h][0]=e0/s; Pi_S[h][1]=e1/s; Pi_S[h][2]=e2/s;
        }
        __syncthreads();   // b3

        // ---- C: cw exp+sum partials; wave0 does allocation scan ----
        if (tid < 128) {
            float ev = __expf(cw_S[tid] - fmaxf(wred[0][0], wred[1][0]));
            cw_S[tid] = ev;
            float s = ev;
            #pragma unroll
            for (int mk = 1; mk < 64; mk <<= 1) s += __shfl_xor(s,mk);
            if (lane == 0) wred[wv][1] = s;
        }
        if (wv == 0) {
            float x0 = srt_S[2*lane], x1 = srt_S[2*lane+1];
            float pp = x0*x1;
            float sc = pp;
            #pragma unroll
            for (int off = 1; off < 64; off <<= 1) {
                float y = __shfl_up(sc, off);
                if (lane >= off) sc *= y;
            }
            float excl = __shfl_up(sc, 1);
            if (lane == 0) excl = 1.f;
            aS_S[2*lane]   = (1.f - x0)*excl;
            aS_S[2*lane+1] = (1.f - x1)*excl*x0;
        }
        __syncthreads();   // b4

        // ---- E: write weighting ww + sum partials ----
        if (tid < 128) {
            float cwsum = wred[0][1] + wred[1][1];
            float alloc = aS_S[rk_S[tid]];
            float ga = scal_S[1], gw = scal_S[2];
            float w = gw*(ga*alloc + (1.f-ga)*cw_S[tid]/cwsum);
            ww_S[tid] = w;
            float s = w;
            #pragma unroll
            for (int mk = 1; mk < 64; mk <<= 1) s += __shfl_xor(s,mk);
            if (lane == 0) wred[wv][0] = s;
        }
        __syncthreads();   // b5

        // ---- G: precedence; M erase/write + read-key dots + new norm ----
        if (tid < 128) {
            float sww = wred[0][0] + wred[1][0];
            p_S[tid] = (1.f - sww)*p_S[tid] + ww_S[tid];
        }
        {
            const int cb = (q8&1)*64, ch = q8>>1;
            const float* ep  = &e_S[ch][cb];
            const float* vp  = &v_S[ch][cb];
            const float* k0p = &Kr_S[0][ch][cb];
            const float* k1p = &Kr_S[1][ch][cb];
            const float* k2p = &Kr_S[2][ch][cb];
            const float* k3p = &Kr_S[3][ch][cb];
            float wwm = ww_S[m8];
            float nrm=0.f, d0=0.f, d1=0.f, d2=0.f, d3=0.f;
            #pragma unroll
            for (int c = 0; c < 16; ++c) {
                float4 x  = Mreg[c];
                float4 ee = *(const float4*)(ep + 4*c);
                float4 vv = *(const float4*)(vp + 4*c);
                x.x = x.x*(1.f - wwm*ee.x) + wwm*vv.x;
                x.y = x.y*(1.f - wwm*ee.y) + wwm*vv.y;
                x.z = x.z*(1.f - wwm*ee.z) + wwm*vv.z;
                x.w = x.w*(1.f - wwm*ee.w) + wwm*vv.w;
                Mreg[c] = x;
                nrm += x.x*x.x + x.y*x.y + x.z*x.z + x.w*x.w;
                float4 k0 = *(const float4*)(k0p + 4*c);
                float4 k1 = *(const float4*)(k1p + 4*c);
                float4 k2 = *(const float4*)(k2p + 4*c);
                float4 k3 = *(const float4*)(k3p + 4*c);
                d0 += x.x*k0.x + x.y*k0.y + x.z*k0.z + x.w*k0.w;
                d1 += x.x*k1.x + x.y*k1.y + x.z*k1.z + x.w*k1.w;
                d2 += x.x*k2.x + x.y*k2.y + x.z*k2.z + x.w*k2.w;
                d3 += x.x*k3.x + x.y*k3.y + x.z*k3.z + x.w*k3.w;
            }
            nrm += __shfl_xor(nrm,1); nrm += __shfl_xor(nrm,2); nrm += __shfl_xor(nrm,4);
            d0  += __shfl_xor(d0,1);  d0  += __shfl_xor(d0,2);  d0  += __shfl_xor(d0,4);
            d1  += __shfl_xor(d1,1);  d1  += __shfl_xor(d1,2);  d1  += __shfl_xor(d1,4);
            d2  += __shfl_xor(d2,1);  d2  += __shfl_xor(d2,2);  d2  += __shfl_xor(d2,4);
            d3  += __shfl_xor(d3,1);  d3  += __shfl_xor(d3,2);  d3  += __shfl_xor(d3,4);
            if (q8 == 4) Mn2_S[m8] = sqrtf(nrm);
            else if (q8 < 4) dotK_S[q8][m8] = (q8==0) ? d0 : ((q8==1) ? d1 : ((q8==2) ? d2 : d3));
        }
        __syncthreads();   // b6

        // ---- H: link matrix update (LDS) + bwd partials ----
        {
            const int j2 = tid & 127, w8 = tid >> 7;
            float wwj = ww_S[j2], pj = p_S[j2];
            float b0=0.f,b1=0.f,b2=0.f,b3=0.f;
            #pragma unroll 8
            for (int s = 0; s < 16; ++s) {
                int i2 = w8 + 8*s;
                float lold = Lm[i2*LPAD + j2];
                float wwi = ww_S[i2];
                float ln = (1.f - wwi - wwj)*lold + wwi*pj;
                Lm[i2*LPAD + j2] = ln;
                b0 += ln*wr_S[0][i2];
                b1 += ln*wr_S[1][i2];
                b2 += ln*wr_S[2][i2];
                b3 += ln*wr_S[3][i2];
            }
            float* sp = scr + w8*SROW + j2;
            sp[0]=b0; sp[132]=b1; sp[264]=b2; sp[396]=b3;
        }
        __syncthreads();   // b7

        // ---- I: bwd combine; fwd (LDS rows); content-read scores + max ----
        if (tid < 512) {
            int h = tid>>7, mm = tid&127;
            float s = 0.f;
            #pragma unroll
            for (int g = 0; g < 8; ++g) s += scr[g*SROW + h*132 + mm];
            bwd_S[h][mm] = s;
        }
        {
            const float* Lr = Lm + m8*LPAD + q8*16;
            float f0=0.f,f1=0.f,f2=0.f,f3=0.f;
            #pragma unroll
            for (int c = 0; c < 4; ++c) {
                float4 lv = *(const float4*)(Lr + 4*c);
                int jb = q8*16 + 4*c;
                float4 w0 = *(const float4*)&wr_S[0][jb];
                float4 w1 = *(const float4*)&wr_S[1][jb];
                float4 w2 = *(const float4*)&wr_S[2][jb];
                float4 w3 = *(const float4*)&wr_S[3][jb];
                f0 += lv.x*w0.x + lv.y*w0.y + lv.z*w0.z + lv.w*w0.w;
                f1 += lv.x*w1.x + lv.y*w1.y + lv.z*w1.z + lv.w*w1.w;
                f2 += lv.x*w2.x + lv.y*w2.y + lv.z*w2.z + lv.w*w2.w;
                f3 += lv.x*w3.x + lv.y*w3.y + lv.z*w3.z + lv.w*w3.w;
            }
            f0 += __shfl_xor(f0,1); f0 += __shfl_xor(f0,2); f0 += __shfl_xor(f0,4);
            f1 += __shfl_xor(f1,1); f1 += __shfl_xor(f1,2); f1 += __shfl_xor(f1,4);
            f2 += __shfl_xor(f2,1); f2 += __shfl_xor(f2,2); f2 += __shfl_xor(f2,4);
            f3 += __shfl_xor(f3,1); f3 += __shfl_xor(f3,2); f3 += __shfl_xor(f3,4);
            if (q8 < 4) fwd_S[q8][m8] = (q8==0) ? f0 : ((q8==1) ? f1 : ((q8==2) ? f2 : f3));
        }
        if (tid < 512) {
            int h = tid>>7, mm = tid&127;
            scv = Br_S[h]*dotK_S[h][mm]/(Mn2_S[mm]*KrN_S[h] + 1e-8f);
            float mxv = scv;
            #pragma unroll
            for (int mk = 1; mk < 64; mk <<= 1) mxv = fmaxf(mxv, __shfl_xor(mxv,mk));
            if (lane == 0) wred[wv][0] = mxv;
        }
        __syncthreads();   // b8

        // ---- J: content-read exp + sum ----
        if (tid < 512) {
            int h = tid>>7;
            float hmax = fmaxf(wred[2*h][0], wred[2*h+1][0]);
            ev2 = __expf(scv - hmax);
            float s = ev2;
            #pragma unroll
            for (int mk = 1; mk < 64; mk <<= 1) s += __shfl_xor(s,mk);
            if (lane == 0) wred[wv][1] = s;
        }
        __syncthreads();   // b9

        // ---- K: new read weights ----
        if (tid < 512) {
            int h = tid>>7, mm = tid&127;
            float hsum = wred[2*h][1] + wred[2*h+1][1];
            float cr = ev2/hsum;
            wr_S[h][mm] = Pi_S[h][0]*bwd_S[h][mm] + Pi_S[h][1]*cr + Pi_S[h][2]*fwd_S[h][mm];
        }
        __syncthreads();   // b10

        // ---- M: read vectors (register M, 3-xor row tree + 16-wave scratch) ----
        {
            float srtm = wr_S[0][m8] + wr_S[1][m8] + wr_S[2][m8] + wr_S[3][m8];
            float* sp = scr + wv*SROW + q8*68;
            #pragma unroll
            for (int c = 0; c < 16; ++c) {
                float v0 = srtm*Mreg[c].x;
                float v1 = srtm*Mreg[c].y;
                float v2 = srtm*Mreg[c].z;
                float v3 = srtm*Mreg[c].w;
                #pragma unroll
                for (int mk = 8; mk < 64; mk <<= 1) {
                    v0 += __shfl_xor(v0,mk); v1 += __shfl_xor(v1,mk);
                    v2 += __shfl_xor(v2,mk); v3 += __shfl_xor(v3,mk);
                }
                if (lane < 8) *(float4*)(sp + 4*c) = make_float4(v0,v1,v2,v3);
            }
        }
        __syncthreads();   // b11

        // ---- N: combine r over 16 waves ----
        if (tid < 512) {
            int off = (tid>>6)*68 + (tid&63);
            float r = 0.f;
            #pragma unroll
            for (int w = 0; w < 16; ++w) r += scr[w*SROW + off];
            r_S[tid] = r;
        }
        __syncthreads();   // b12

        // ---- O: actor logits (one wave per logit, Wa from global) ----
        {
            const float* war = Wa + (wv << 9);
            float acc = 0.f;
            #pragma unroll
            for (int j = 0; j < 8; ++j) {
                int d = lane + (j << 6);
                acc += war[d]*r_S[d];
            }
            #pragma unroll
            for (int mk = 1; mk < 64; mk <<= 1) acc += __shfl_xor(acc,mk);
            if (lane == 0) logit_S[wv] = acc + ba_S[wv];
        }
        __syncthreads();   // b13

        // ---- P: actor softmax + output ----
        if (tid == 0) {
            float mx = logit_S[0];
            #pragma unroll
            for (int k2 = 1; k2 < 16; ++k2) mx = fmaxf(mx, logit_S[k2]);
            float ex[16]; float s = 0.f;
            #pragma unroll
            for (int k2 = 0; k2 < 16; ++k2) { ex[k2] = __expf(logit_S[k2]-mx); s += ex[k2]; }
            float inv = 1.f/s;
            float* op = out + (size_t)(t*NB + n)*17;
            #pragma unroll
            for (int k2 = 0; k2 < 16; ++k2) op[k2] = ex[k2]*inv;
        }
    }
}

// ---------------- host launch ----------------
extern "C" void kernel_launch(void* const* d_in, const int* in_sizes, int n_in,
                              void* d_out, int out_size, void* d_ws, size_t ws_size,
                              hipStream_t stream) {
    const float* inp  = (const float*)d_in[0];
    const float* w_ih = (const float*)d_in[1];
    const float* w_hh = (const float*)d_in[2];
    const float* b_ih = (const float*)d_in[3];
    const float* b_hh = (const float*)d_in[4];
    const float* Wf   = (const float*)d_in[5];
    const float* bf   = (const float*)d_in[6];
    const float* Wa   = (const float*)d_in[7];
    const float* ba   = (const float*)d_in[8];
    const float* Wc   = (const float*)d_in[9];
    const float* bc   = (const float*)d_in[10];
    float* out = (float*)d_out;

    float* ws = (float*)d_ws;
    float* wihT   = ws;                       // 64*1536
    float* whhT   = ws + 98304;               // 512*1536
    float* h_all  = ws + 884736;              // 1024*512
    float* xi_all = ws + 1409024;             // 1024*3607

    static int dynset = 0;
    if (!dynset) {
        hipFuncSetAttribute(reinterpret_cast<const void*>(k_mem),
                            hipFuncAttributeMaxDynamicSharedMemorySize,
                            DYN_FLOATS*4);
        dynset = 1;
    }

    dim3 tb(32, 8);
    k_transpose<<<dim3(48, 2),  tb, 0, stream>>>(w_ih, wihT, G3, DOBS);
    k_transpose<<<dim3(48, 16), tb, 0, stream>>>(w_hh, whhT, G3, HID);
    k_gru<<<NB, 512, 0, stream>>>(inp, wihT, whhT, b_ih, b_hh, h_all);
    k_xi<<<dim3(57, 8), 256, 0, stream>>>(h_all, Wf, bf, xi_all);
    k_val<<<TT*NB, 64, 0, stream>>>(h_all, Wc, bc, out);
    k_mem<<<NB, 1024, DYN_FLOATS*4, stream>>>(xi_all, Wa, ba, out);
}

// Round 2
// 1842.108 us; speedup vs baseline: 1.2343x; 1.1426x over previous
//
#include <hip/hip_runtime.h>
#include <math.h>

#define TT 32
#define NB 32
#define DOBS 64
#define HID 512
#define HEADS 4
#define MEM 128
#define NACT 16
#define XID 3607
#define G3 1536

__device__ __forceinline__ float sigm(float x){ return 1.0f/(1.0f+__expf(-x)); }
__device__ __forceinline__ float splus(float x){ return fmaxf(x,0.f) + log1pf(__expf(-fabsf(x))); }

// full-wave (64) reductions; xor-32 level on the VALU via v_permlane32_swap_b32
__device__ __forceinline__ float wsum64(float s){
    s += __shfl_xor(s,1); s += __shfl_xor(s,2); s += __shfl_xor(s,4);
    s += __shfl_xor(s,8); s += __shfl_xor(s,16);
    float t = s;
    asm volatile("v_permlane32_swap_b32 %0, %1" : "+v"(s), "+v"(t));
    return s + t;
}
__device__ __forceinline__ float wmax64(float s){
    s = fmaxf(s, __shfl_xor(s,1)); s = fmaxf(s, __shfl_xor(s,2)); s = fmaxf(s, __shfl_xor(s,4));
    s = fmaxf(s, __shfl_xor(s,8)); s = fmaxf(s, __shfl_xor(s,16));
    float t = s;
    asm volatile("v_permlane32_swap_b32 %0, %1" : "+v"(s), "+v"(t));
    return fmaxf(s, t);
}

// ---------------- transpose (32x32 tiles via LDS) ----------------
__global__ __launch_bounds__(256) void k_transpose(const float* __restrict__ src,
                                                   float* __restrict__ dst, int R, int C)
{
    __shared__ float tile[32][33];
    int r0 = blockIdx.x*32, c0 = blockIdx.y*32;
    int tx = threadIdx.x, ty = threadIdx.y;
    #pragma unroll
    for (int yy = 0; yy < 32; yy += 8) {
        int r = r0 + ty + yy, c = c0 + tx;
        if (r < R && c < C) tile[ty+yy][tx] = src[(size_t)r*C + c];
    }
    __syncthreads();
    #pragma unroll
    for (int yy = 0; yy < 32; yy += 8) {
        int c = c0 + ty + yy, r = r0 + tx;
        if (r < R && c < C) dst[(size_t)c*R + r] = tile[tx][ty+yy];
    }
}

// ---------------- GRU: one block per batch chain ----------------
__global__ __launch_bounds__(512) void k_gru(
    const float* __restrict__ x,
    const float* __restrict__ wihT,   // [64][1536]
    const float* __restrict__ whhT,   // [512][1536]
    const float* __restrict__ b_ih,
    const float* __restrict__ b_hh,
    float* __restrict__ h_all)        // [T*N][512]
{
    const int n = blockIdx.x;
    const int tid = threadIdx.x;
    __shared__ float hS[512];
    __shared__ float xS[64];
    __shared__ float grS[512], gzS[512], giN[512], ghN[512];
    hS[tid] = 0.f;

    for (int t = 0; t < TT; ++t) {
        if (tid < 64) xS[tid] = x[((size_t)t*NB + n)*DOBS + tid];
        __syncthreads();
        if (tid < 384) {
            const int r0 = tid*4;
            float4 aI = *(const float4*)(b_ih + r0);
            float4 aH = *(const float4*)(b_hh + r0);
            #pragma unroll 4
            for (int k = 0; k < DOBS; ++k) {
                float xv = xS[k];
                float4 w = *(const float4*)(wihT + (size_t)k*G3 + r0);
                aI.x += w.x*xv; aI.y += w.y*xv; aI.z += w.z*xv; aI.w += w.w*xv;
            }
            #pragma unroll 4
            for (int k = 0; k < HID; ++k) {
                float hv = hS[k];
                float4 w = *(const float4*)(whhT + (size_t)k*G3 + r0);
                aH.x += w.x*hv; aH.y += w.y*hv; aH.z += w.z*hv; aH.w += w.w*hv;
            }
            if (r0 < 512) {
                grS[r0+0]=aI.x+aH.x; grS[r0+1]=aI.y+aH.y; grS[r0+2]=aI.z+aH.z; grS[r0+3]=aI.w+aH.w;
            } else if (r0 < 1024) {
                int b = r0-512;
                gzS[b+0]=aI.x+aH.x; gzS[b+1]=aI.y+aH.y; gzS[b+2]=aI.z+aH.z; gzS[b+3]=aI.w+aH.w;
            } else {
                int b = r0-1024;
                giN[b+0]=aI.x; giN[b+1]=aI.y; giN[b+2]=aI.z; giN[b+3]=aI.w;
                ghN[b+0]=aH.x; ghN[b+1]=aH.y; ghN[b+2]=aH.z; ghN[b+3]=aH.w;
            }
        }
        __syncthreads();
        {
            const int d = tid;
            float rg = sigm(grS[d]);
            float zg = sigm(gzS[d]);
            float ng = tanhf(giN[d] + rg*ghN[d]);
            float hn = (1.f-zg)*ng + zg*hS[d];
            hS[d] = hn;
            h_all[((size_t)t*NB + n)*HID + d] = hn;
        }
        __syncthreads();
    }
}

// ---------------- xi = relu(h_all) @ Wf^T + bf  (128x64 tiles, 8x4 acc) ----------------
__global__ __launch_bounds__(256) void k_xi(
    const float* __restrict__ h_all,
    const float* __restrict__ Wf,
    const float* __restrict__ bf,
    float* __restrict__ xi_all)
{
    __shared__ float As[16][132];
    __shared__ float Bs[16][68];
    const int jt = blockIdx.x * 64;
    const int it = blockIdx.y * 128;
    const int tid = threadIdx.x;
    const int lc = tid & 15, lr = tid >> 4;
    const int tx = tid & 15, ty = tid >> 4;
    float acc[8][4] = {};

    for (int k0 = 0; k0 < HID; k0 += 16) {
        #pragma unroll
        for (int s = 0; s < 8; ++s) {
            int i = lr*8 + s;
            As[lc][i] = fmaxf(h_all[(size_t)(it + i)*HID + k0 + lc], 0.f);
        }
        #pragma unroll
        for (int s = 0; s < 4; ++s) {
            int j = lr*4 + s;
            Bs[lc][j] = (jt + j < XID) ? Wf[(size_t)(jt + j)*HID + k0 + lc] : 0.f;
        }
        __syncthreads();
        #pragma unroll
        for (int k = 0; k < 16; ++k) {
            float a[8], b[4];
            #pragma unroll
            for (int u = 0; u < 8; ++u) a[u] = As[k][ty*8+u];
            #pragma unroll
            for (int v = 0; v < 4; ++v) b[v] = Bs[k][tx*4+v];
            #pragma unroll
            for (int u = 0; u < 8; ++u)
                #pragma unroll
                for (int v = 0; v < 4; ++v) acc[u][v] += a[u]*b[v];
        }
        __syncthreads();
    }
    #pragma unroll
    for (int u = 0; u < 8; ++u)
        #pragma unroll
        for (int v = 0; v < 4; ++v) {
            int i = it + ty*8 + u, j = jt + tx*4 + v;
            if (j < XID) xi_all[(size_t)i*XID + j] = acc[u][v] + bf[j];
        }
}

// ---------------- critic head ----------------
__global__ __launch_bounds__(64) void k_val(
    const float* __restrict__ h_all, const float* __restrict__ Wc,
    const float* __restrict__ bc, float* __restrict__ out)
{
    const int row = blockIdx.x;
    const int lane = threadIdx.x;
    float acc = 0.f;
    for (int d = lane; d < HID; d += 64) acc += h_all[(size_t)row*HID + d]*Wc[d];
    for (int off = 32; off; off >>= 1) acc += __shfl_down(acc, off);
    if (lane == 0) out[(size_t)row*17 + 16] = acc + bc[0];
}

// ---------------- memory recurrence: 1024 threads, M in registers, L in LDS ----------------
#define LPAD 132
#define SROW 544
#define DYN_FLOATS (128*LPAD + 16*SROW)
// chunked operand layout: column d -> chunk (d>>6), offset (d&63); row stride 68 (bank-spread)
#define CIDX(d) ((((d)>>6)*68) + ((d)&63))

__global__ __launch_bounds__(1024) void k_mem(
    const float* __restrict__ xi_all, // [1024][3607]
    const float* __restrict__ Wa,     // [16][512]
    const float* __restrict__ ba,     // [16]
    float* __restrict__ out)          // [1024][17]
{
    extern __shared__ __align__(16) float dynS[];
    float* Lm  = dynS;                // [128][LPAD]
    float* scr = dynS + 128*LPAD;     // [16][SROW]

    const int n = blockIdx.x;
    const int tid = threadIdx.x;
    const int lane = tid & 63;
    const int wv = tid >> 6;          // 0..15
    const int m8 = tid >> 3;          // row 0..127
    const int q8 = tid & 7;           // col-group 0..7 (64 cols each)

    // chunked-padded operands: conflict-free for the per-q8 float4 reads
    __shared__ __align__(16) float KrC[4*544];            // [head][8 chunks][68]
    __shared__ __align__(16) float kwC[544], eC[544], vC[544];
    __shared__ __align__(16) float wrC[4*136];            // [head][2 chunks][68]
    __shared__ __align__(16) float r_S[512];
    __shared__ float dotK_S[4][132], fwd_S[4][132], bwd_S[4][132];
    __shared__ float u_S[128], ww_S[128], p_S[128], cw_S[128], srt_S[128], aS_S[128];
    __shared__ float Mn2_S[128], dw_S[128];
    __shared__ int   rk_S[128];
    __shared__ float wred[16][6];
    __shared__ float scal_S[8];                 // 0=bw 1=ga 2=gw 3=kwn
    __shared__ float PiRaw[12];
    __shared__ float Pi_S[4][3], Br_S[4], KrN_S[4], F_S[4];
    __shared__ float ba_S[16], logit_S[16];

    // M[m8][q8*64 + 4c + j], c<16 : 16 float4 per thread (64 VGPRs)
    float4 Mreg[16];
    #pragma unroll
    for (int i = 0; i < 16; ++i) Mreg[i] = make_float4(0.f,0.f,0.f,0.f);

    for (int i = tid; i < 128*LPAD; i += 1024) Lm[i] = 0.f;
    if (tid < 16) ba_S[tid] = ba[tid];
    if (tid < 128) { u_S[tid]=0.f; ww_S[tid]=0.f; p_S[tid]=0.f; Mn2_S[tid]=0.f; }
    if (tid < 512) wrC[(tid>>7)*136 + CIDX(tid&127)] = 0.f;

    // Wa resident in registers: wave wv owns logit wv; lane holds d = lane+64j
    float waR[8];
    #pragma unroll
    for (int j = 0; j < 8; ++j) waR[j] = Wa[(wv<<9) + lane + (j<<6)];

    // extra-scalar mapping (23 scalars on threads 1000..1022)
    const bool hasEx = (tid >= 1000 && tid < 1023);
    int exIdx = 0;
    if (tid >= 1000 && tid < 1004)      exIdx = 2048 + (tid - 1000);  // Br
    else if (tid == 1004)               exIdx = 2564;                 // bw
    else if (tid >= 1005 && tid < 1023) exIdx = 3589 + (tid - 1005);  // F(4),ga,gw,Pi(12)

    // initial prefetch (t = 0)
    const float* xi0 = xi_all + (size_t)n*XID;
    float pKrA = xi0[tid];
    float pKrB = xi0[1024 + tid];
    float pkw = 0.f, pv = 0.f, pe = 0.f;
    if (tid < 512) { pkw = xi0[2052 + tid]; pv = xi0[3077 + tid]; }
    else           { pe  = xi0[2565 + (tid - 512)]; }
    float pex = hasEx ? xi0[exIdx] : 0.f;
    __syncthreads();   // b0: LDS init done

    for (int t = 0; t < TT; ++t) {
        float scv = 0.f, ev2 = 0.f;

        // ---- P0: reg -> LDS with activations; norm partials; issue prefetch(t+1) ----
        {
            int d = tid & 511, hh = tid >> 9;
            int co = CIDX(d);
            KrC[hh*544 + co]     = pKrA;
            KrC[(2+hh)*544 + co] = pKrB;
        }
        if (tid < 512) { int co = CIDX(tid); kwC[co] = pkw; vC[co] = pv; }
        else { int s2 = tid - 512; int co = CIDX(s2); eC[co] = sigm(pe); }
        if (hasEx) {
            if (tid < 1004)      Br_S[tid-1000] = splus(pex);
            else if (tid==1004)  scal_S[0] = splus(pex);
            else if (tid < 1009) F_S[tid-1005] = sigm(pex);
            else if (tid==1009)  scal_S[1] = sigm(pex);
            else if (tid==1010)  scal_S[2] = sigm(pex);
            else                 PiRaw[tid-1011] = pex;
        }
        {
            float sA = wsum64(pKrA*pKrA);
            float sB = wsum64(pKrB*pKrB);
            float sK = wsum64(pkw*pkw);
            if (lane == 0) { wred[wv][0]=sA; wred[wv][1]=sB; wred[wv][2]=sK; }
        }
        {   // prefetch next step
            int tn = (t+1 < TT) ? (t+1) : t;
            const float* xin = xi_all + (size_t)(tn*NB + n)*XID;
            pKrA = xin[tid]; pKrB = xin[1024 + tid];
            if (tid < 512) { pkw = xin[2052 + tid]; pv = xin[3077 + tid]; }
            else           { pe  = xin[2565 + (tid - 512)]; }
            if (hasEx) pex = xin[exIdx];
        }
        __syncthreads();   // b1

        // ---- A: finalize norms; usage update (old wr/ww); kw dots on OLD M ----
        if (tid < 4) {
            float s = 0.f;
            #pragma unroll
            for (int w = 0; w < 8; ++w) s += wred[(tid&1)*8 + w][tid>>1];
            KrN_S[tid] = sqrtf(s);
        } else if (tid == 4) {
            float s = 0.f;
            #pragma unroll
            for (int w = 0; w < 8; ++w) s += wred[w][2];
            scal_S[3] = sqrtf(s);
        }
        if (tid < 128) {
            int co = CIDX(tid);
            float psi = (1.f - F_S[0]*wrC[co])      * (1.f - F_S[1]*wrC[136+co])
                      * (1.f - F_S[2]*wrC[272+co])  * (1.f - F_S[3]*wrC[408+co]);
            float uu = u_S[tid], w = ww_S[tid];
            u_S[tid] = (uu + w - uu*w)*psi;
        }
        {
            const float* kwp = kwC + q8*68;
            float dw = 0.f;
            #pragma unroll
            for (int c = 0; c < 16; ++c) {
                float4 x = Mreg[c];
                float4 kk = *(const float4*)(kwp + 4*c);
                dw += x.x*kk.x + x.y*kk.y + x.z*kk.z + x.w*kk.w;
            }
            dw += __shfl_xor(dw,1); dw += __shfl_xor(dw,2); dw += __shfl_xor(dw,4);
            if (q8 == 0) dw_S[m8] = dw;
        }
        __syncthreads();   // b2

        // ---- B: cw scores (old-M norm carried in Mn2_S); parallel rank; cwmax; Pi softmax ----
        {
            float um = u_S[m8];
            int rk = 0;
            #pragma unroll
            for (int jj = 0; jj < 16; ++jj) {
                int j = jj*8 + q8;
                float uj = u_S[j];
                rk += (uj < um || (uj == um && j < m8)) ? 1 : 0;
            }
            rk += __shfl_xor(rk,1); rk += __shfl_xor(rk,2); rk += __shfl_xor(rk,4);
            if (q8 == 0) { rk_S[m8] = rk; srt_S[rk] = um; }
        }
        if (tid < 128) {
            float cwv = scal_S[0]*dw_S[tid]/(Mn2_S[tid]*scal_S[3] + 1e-8f);
            cw_S[tid] = cwv;
            float mx = wmax64(cwv);
            if (lane == 0) wred[wv][0] = mx;
        } else if (tid >= 136 && tid < 140) {
            int h = tid - 136;
            float p0 = PiRaw[3*h], p1 = PiRaw[3*h+1], p2 = PiRaw[3*h+2];
            float mx = fmaxf(p0, fmaxf(p1, p2));
            float e0=__expf(p0-mx), e1=__expf(p1-mx), e2=__expf(p2-mx);
            float s = e0+e1+e2;
            Pi_S[h][0]=e0/s; Pi_S[h][1]=e1/s; Pi_S[h][2]=e2/s;
        }
        __syncthreads();   // b3

        // ---- C: cw exp+sum partials; wave0 does allocation scan ----
        if (tid < 128) {
            float ev = __expf(cw_S[tid] - fmaxf(wred[0][0], wred[1][0]));
            cw_S[tid] = ev;
            float s = wsum64(ev);
            if (lane == 0) wred[wv][1] = s;
        }
        if (wv == 0) {
            float x0 = srt_S[2*lane], x1 = srt_S[2*lane+1];
            float pp = x0*x1;
            float sc = pp;
            #pragma unroll
            for (int off = 1; off < 64; off <<= 1) {
                float y = __shfl_up(sc, off);
                if (lane >= off) sc *= y;
            }
            float excl = __shfl_up(sc, 1);
            if (lane == 0) excl = 1.f;
            aS_S[2*lane]   = (1.f - x0)*excl;
            aS_S[2*lane+1] = (1.f - x1)*excl*x0;
        }
        __syncthreads();   // b4

        // ---- E: write weighting ww + sum partials ----
        if (tid < 128) {
            float cwsum = wred[0][1] + wred[1][1];
            float alloc = aS_S[rk_S[tid]];
            float ga = scal_S[1], gw = scal_S[2];
            float w = gw*(ga*alloc + (1.f-ga)*cw_S[tid]/cwsum);
            ww_S[tid] = w;
            float s = wsum64(w);
            if (lane == 0) wred[wv][0] = s;
        }
        __syncthreads();   // b5

        // ---- G: precedence; M erase/write + read-key dots + new norm ----
        if (tid < 128) {
            float sww = wred[0][0] + wred[1][0];
            p_S[tid] = (1.f - sww)*p_S[tid] + ww_S[tid];
        }
        {
            const int base = q8*68;
            const float* ep  = eC + base;
            const float* vp  = vC + base;
            const float* k0p = KrC + base;
            const float* k1p = KrC + 544 + base;
            const float* k2p = KrC + 1088 + base;
            const float* k3p = KrC + 1632 + base;
            float wwm = ww_S[m8];
            float nrm=0.f, d0=0.f, d1=0.f, d2=0.f, d3=0.f;
            #pragma unroll
            for (int c = 0; c < 16; ++c) {
                float4 x  = Mreg[c];
                float4 ee = *(const float4*)(ep + 4*c);
                float4 vv = *(const float4*)(vp + 4*c);
                x.x = x.x*(1.f - wwm*ee.x) + wwm*vv.x;
                x.y = x.y*(1.f - wwm*ee.y) + wwm*vv.y;
                x.z = x.z*(1.f - wwm*ee.z) + wwm*vv.z;
                x.w = x.w*(1.f - wwm*ee.w) + wwm*vv.w;
                Mreg[c] = x;
                nrm += x.x*x.x + x.y*x.y + x.z*x.z + x.w*x.w;
                float4 k0 = *(const float4*)(k0p + 4*c);
                float4 k1 = *(const float4*)(k1p + 4*c);
                float4 k2 = *(const float4*)(k2p + 4*c);
                float4 k3 = *(const float4*)(k3p + 4*c);
                d0 += x.x*k0.x + x.y*k0.y + x.z*k0.z + x.w*k0.w;
                d1 += x.x*k1.x + x.y*k1.y + x.z*k1.z + x.w*k1.w;
                d2 += x.x*k2.x + x.y*k2.y + x.z*k2.z + x.w*k2.w;
                d3 += x.x*k3.x + x.y*k3.y + x.z*k3.z + x.w*k3.w;
            }
            nrm += __shfl_xor(nrm,1); nrm += __shfl_xor(nrm,2); nrm += __shfl_xor(nrm,4);
            d0  += __shfl_xor(d0,1);  d0  += __shfl_xor(d0,2);  d0  += __shfl_xor(d0,4);
            d1  += __shfl_xor(d1,1);  d1  += __shfl_xor(d1,2);  d1  += __shfl_xor(d1,4);
            d2  += __shfl_xor(d2,1);  d2  += __shfl_xor(d2,2);  d2  += __shfl_xor(d2,4);
            d3  += __shfl_xor(d3,1);  d3  += __shfl_xor(d3,2);  d3  += __shfl_xor(d3,4);
            if (q8 == 4) Mn2_S[m8] = sqrtf(nrm);
            else if (q8 < 4) dotK_S[q8][m8] = (q8==0) ? d0 : ((q8==1) ? d1 : ((q8==2) ? d2 : d3));
        }
        __syncthreads();   // b6

        // ---- H: link matrix update (contiguous 16-row blocks; wr/ww staged as float4) ----
        {
            const int j2 = tid & 127, w8 = tid >> 7;
            float wwj = ww_S[j2], pj = p_S[j2];
            float b0=0.f,b1=0.f,b2=0.f,b3=0.f;
            #pragma unroll
            for (int c2 = 0; c2 < 4; ++c2) {
                const int r0 = (w8<<4) + (c2<<2);
                const int bidx = CIDX(r0);
                float4 wwv = *(const float4*)&ww_S[r0];
                float4 w0v = *(const float4*)&wrC[bidx];
                float4 w1v = *(const float4*)&wrC[136+bidx];
                float4 w2v = *(const float4*)&wrC[272+bidx];
                float4 w3v = *(const float4*)&wrC[408+bidx];
                #pragma unroll
                for (int s4 = 0; s4 < 4; ++s4) {
                    int i2 = r0 + s4;
                    float wwi = (s4==0)?wwv.x:(s4==1)?wwv.y:(s4==2)?wwv.z:wwv.w;
                    float lold = Lm[i2*LPAD + j2];
                    float ln = (1.f - wwi - wwj)*lold + wwi*pj;
                    Lm[i2*LPAD + j2] = ln;
                    b0 += ln*((s4==0)?w0v.x:(s4==1)?w0v.y:(s4==2)?w0v.z:w0v.w);
                    b1 += ln*((s4==0)?w1v.x:(s4==1)?w1v.y:(s4==2)?w1v.z:w1v.w);
                    b2 += ln*((s4==0)?w2v.x:(s4==1)?w2v.y:(s4==2)?w2v.z:w2v.w);
                    b3 += ln*((s4==0)?w3v.x:(s4==1)?w3v.y:(s4==2)?w3v.z:w3v.w);
                }
            }
            float* sp = scr + w8*SROW + j2;
            sp[0]=b0; sp[132]=b1; sp[264]=b2; sp[396]=b3;
        }
        __syncthreads();   // b7

        // ---- I: bwd combine; fwd (LDS rows); content-read scores + max ----
        if (tid < 512) {
            int h = tid>>7, mm = tid&127;
            float s = 0.f;
            #pragma unroll
            for (int g = 0; g < 8; ++g) s += scr[g*SROW + h*132 + mm];
            bwd_S[h][mm] = s;
        }
        {
            const float* Lr = Lm + m8*LPAD + q8*16;
            const int wb = ((q8>>2)*68) + ((q8&3)<<4);
            float f0=0.f,f1=0.f,f2=0.f,f3=0.f;
            #pragma unroll
            for (int c = 0; c < 4; ++c) {
                float4 lv = *(const float4*)(Lr + 4*c);
                float4 w0 = *(const float4*)&wrC[wb + 4*c];
                float4 w1 = *(const float4*)&wrC[136 + wb + 4*c];
                float4 w2 = *(const float4*)&wrC[272 + wb + 4*c];
                float4 w3 = *(const float4*)&wrC[408 + wb + 4*c];
                f0 += lv.x*w0.x + lv.y*w0.y + lv.z*w0.z + lv.w*w0.w;
                f1 += lv.x*w1.x + lv.y*w1.y + lv.z*w1.z + lv.w*w1.w;
                f2 += lv.x*w2.x + lv.y*w2.y + lv.z*w2.z + lv.w*w2.w;
                f3 += lv.x*w3.x + lv.y*w3.y + lv.z*w3.z + lv.w*w3.w;
            }
            f0 += __shfl_xor(f0,1); f0 += __shfl_xor(f0,2); f0 += __shfl_xor(f0,4);
            f1 += __shfl_xor(f1,1); f1 += __shfl_xor(f1,2); f1 += __shfl_xor(f1,4);
            f2 += __shfl_xor(f2,1); f2 += __shfl_xor(f2,2); f2 += __shfl_xor(f2,4);
            f3 += __shfl_xor(f3,1); f3 += __shfl_xor(f3,2); f3 += __shfl_xor(f3,4);
            if (q8 < 4) fwd_S[q8][m8] = (q8==0) ? f0 : ((q8==1) ? f1 : ((q8==2) ? f2 : f3));
        }
        if (tid < 512) {
            int h = tid>>7, mm = tid&127;
            scv = Br_S[h]*dotK_S[h][mm]/(Mn2_S[mm]*KrN_S[h] + 1e-8f);
            float mxv = wmax64(scv);
            if (lane == 0) wred[wv][0] = mxv;
        }
        __syncthreads();   // b8

        // ---- J: content-read exp + sum ----
        if (tid < 512) {
            int h = tid>>7;
            float hmax = fmaxf(wred[2*h][0], wred[2*h+1][0]);
            ev2 = __expf(scv - hmax);
            float s = wsum64(ev2);
            if (lane == 0) wred[wv][1] = s;
        }
        __syncthreads();   // b9

        // ---- K: new read weights ----
        if (tid < 512) {
            int h = tid>>7, mm = tid&127;
            float hsum = wred[2*h][1] + wred[2*h+1][1];
            float cr = ev2/hsum;
            wrC[h*136 + CIDX(mm)] = Pi_S[h][0]*bwd_S[h][mm] + Pi_S[h][1]*cr + Pi_S[h][2]*fwd_S[h][mm];
        }
        __syncthreads();   // b10

        // ---- M: read vectors (permlane32 pair-reduce over rows; one b64 write per chunk) ----
        {
            const int co = CIDX(m8);
            float srtm = wrC[co] + wrC[136+co] + wrC[272+co] + wrC[408+co];
            float* sp = scr + wv*SROW + q8*68 + ((lane>>5)<<1);
            #pragma unroll
            for (int c = 0; c < 16; ++c) {
                float v0 = srtm*Mreg[c].x;
                float v1 = srtm*Mreg[c].y;
                float v2 = srtm*Mreg[c].z;
                float v3 = srtm*Mreg[c].w;
                asm volatile("v_permlane32_swap_b32 %0, %1" : "+v"(v0), "+v"(v2));
                float A = v0 + v2;            // lanes<32: col 4c+0 pair; lanes>=32: col 4c+2 pair
                asm volatile("v_permlane32_swap_b32 %0, %1" : "+v"(v1), "+v"(v3));
                float B = v1 + v3;            // lanes<32: col 4c+1 pair; lanes>=32: col 4c+3 pair
                A += __shfl_xor(A, 8); A += __shfl_xor(A, 16);
                B += __shfl_xor(B, 8); B += __shfl_xor(B, 16);
                if ((lane & 31) < 8) *(float2*)(sp + 4*c) = make_float2(A, B);
            }
        }
        __syncthreads();   // b11

        // ---- N: combine r over 16 waves ----
        if (tid < 512) {
            int off = ((tid>>6)*68) + (tid&63);
            float r = 0.f;
            #pragma unroll
            for (int w = 0; w < 16; ++w) r += scr[w*SROW + off];
            r_S[tid] = r;
        }
        __syncthreads();   // b12

        // ---- O: actor logits (one wave per logit, Wa in registers) ----
        {
            float acc = 0.f;
            #pragma unroll
            for (int j = 0; j < 8; ++j) acc += waR[j]*r_S[lane + (j<<6)];
            acc = wsum64(acc);
            if (lane == 0) logit_S[wv] = acc + ba_S[wv];
        }
        __syncthreads();   // b13

        // ---- P: actor softmax + output (16 lanes) ----
        if (tid < 16) {
            float lg = logit_S[tid];
            float mx = lg;
            mx = fmaxf(mx, __shfl_xor(mx,1)); mx = fmaxf(mx, __shfl_xor(mx,2));
            mx = fmaxf(mx, __shfl_xor(mx,4)); mx = fmaxf(mx, __shfl_xor(mx,8));
            float ex2 = __expf(lg - mx);
            float s = ex2;
            s += __shfl_xor(s,1); s += __shfl_xor(s,2);
            s += __shfl_xor(s,4); s += __shfl_xor(s,8);
            out[(size_t)(t*NB + n)*17 + tid] = ex2/s;
        }
    }
}

// ---------------- host launch ----------------
extern "C" void kernel_launch(void* const* d_in, const int* in_sizes, int n_in,
                              void* d_out, int out_size, void* d_ws, size_t ws_size,
                              hipStream_t stream) {
    const float* inp  = (const float*)d_in[0];
    const float* w_ih = (const float*)d_in[1];
    const float* w_hh = (const float*)d_in[2];
    const float* b_ih = (const float*)d_in[3];
    const float* b_hh = (const float*)d_in[4];
    const float* Wf   = (const float*)d_in[5];
    const float* bf   = (const float*)d_in[6];
    const float* Wa   = (const float*)d_in[7];
    const float* ba   = (const float*)d_in[8];
    const float* Wc   = (const float*)d_in[9];
    const float* bc   = (const float*)d_in[10];
    float* out = (float*)d_out;

    float* ws = (float*)d_ws;
    float* wihT   = ws;                       // 64*1536
    float* whhT   = ws + 98304;               // 512*1536
    float* h_all  = ws + 884736;              // 1024*512
    float* xi_all = ws + 1409024;             // 1024*3607

    static int dynset = 0;
    if (!dynset) {
        hipFuncSetAttribute(reinterpret_cast<const void*>(k_mem),
                            hipFuncAttributeMaxDynamicSharedMemorySize,
                            DYN_FLOATS*4);
        dynset = 1;
    }

    dim3 tb(32, 8);
    k_transpose<<<dim3(48, 2),  tb, 0, stream>>>(w_ih, wihT, G3, DOBS);
    k_transpose<<<dim3(48, 16), tb, 0, stream>>>(w_hh, whhT, G3, HID);
    k_gru<<<NB, 512, 0, stream>>>(inp, wihT, whhT, b_ih, b_hh, h_all);
    k_xi<<<dim3(57, 8), 256, 0, stream>>>(h_all, Wf, bf, xi_all);
    k_val<<<TT*NB, 64, 0, stream>>>(h_all, Wc, bc, out);
    k_mem<<<NB, 1024, DYN_FLOATS*4, stream>>>(xi_all, Wa, ba, out);
}

// Round 3
// 1387.619 us; speedup vs baseline: 1.6385x; 1.3275x over previous
//
#include <hip/hip_runtime.h>
#include <math.h>

#define TT 32
#define NB 32
#define DOBS 64
#define HID 512
#define HEADS 4
#define MEM 128
#define NACT 16
#define XID 3607
#define G3 1536

__device__ __forceinline__ float sigm(float x){ return 1.0f/(1.0f+__expf(-x)); }
__device__ __forceinline__ float splus(float x){ return fmaxf(x,0.f) + log1pf(__expf(-fabsf(x))); }

// full-wave (64) reductions; xor-32 level on the VALU via v_permlane32_swap_b32
__device__ __forceinline__ float wsum64(float s){
    s += __shfl_xor(s,1); s += __shfl_xor(s,2); s += __shfl_xor(s,4);
    s += __shfl_xor(s,8); s += __shfl_xor(s,16);
    float t = s;
    asm volatile("v_permlane32_swap_b32 %0, %1" : "+v"(s), "+v"(t));
    return s + t;
}
__device__ __forceinline__ float wmax64(float s){
    s = fmaxf(s, __shfl_xor(s,1)); s = fmaxf(s, __shfl_xor(s,2)); s = fmaxf(s, __shfl_xor(s,4));
    s = fmaxf(s, __shfl_xor(s,8)); s = fmaxf(s, __shfl_xor(s,16));
    float t = s;
    asm volatile("v_permlane32_swap_b32 %0, %1" : "+v"(s), "+v"(t));
    return fmaxf(s, t);
}

// ---------------- transpose (32x32 tiles via LDS) ----------------
__global__ __launch_bounds__(256) void k_transpose(const float* __restrict__ src,
                                                   float* __restrict__ dst, int R, int C)
{
    __shared__ float tile[32][33];
    int r0 = blockIdx.x*32, c0 = blockIdx.y*32;
    int tx = threadIdx.x, ty = threadIdx.y;
    #pragma unroll
    for (int yy = 0; yy < 32; yy += 8) {
        int r = r0 + ty + yy, c = c0 + tx;
        if (r < R && c < C) tile[ty+yy][tx] = src[(size_t)r*C + c];
    }
    __syncthreads();
    #pragma unroll
    for (int yy = 0; yy < 32; yy += 8) {
        int c = c0 + ty + yy, r = r0 + tx;
        if (r < R && c < C) dst[(size_t)c*R + r] = tile[tx][ty+yy];
    }
}

// ---------------- GRU: 4 blocks per chain, per-step agent-scope rendezvous ----------------
__global__ __launch_bounds__(384) void k_gru(
    const float* __restrict__ x,
    const float* __restrict__ wihT,   // [64][1536]
    const float* __restrict__ whhT,   // [512][1536]
    const float* __restrict__ b_ih,
    const float* __restrict__ b_hh,
    float* __restrict__ h_all,        // [T*N][512]
    float* hG,                        // [NB][512] exchange buffer
    int* flags)                       // [NB] monotone arrival counters
{
    const int n   = blockIdx.x & 31;
    const int s   = blockIdx.x >> 5;        // h-slice 0..3
    const int tid = threadIdx.x;
    const int kq  = tid / 96;               // k-quarter 0..3
    const int c   = tid % 96;               // chunk 0..95 (4 rows each)
    const int g   = c >> 5;                 // gate 0..2 (r,z,n)
    const int r0  = g*512 + s*128 + (c & 31)*4;  // global gate-row base (float4)

    __shared__ float hS[512];
    __shared__ float xS[64];
    __shared__ float4 pI[4][96];
    __shared__ float4 pH[4][96];
    __shared__ float grS[128], gzS[128], giN[128], ghN[128];

    for (int i = tid; i < 512; i += 384) hS[i] = 0.f;

    for (int t = 0; t < TT; ++t) {
        if (tid < 64) xS[tid] = x[((size_t)t*NB + n)*DOBS + tid];
        __syncthreads();   // hS + xS ready
        {
            float4 aI = make_float4(0.f,0.f,0.f,0.f);
            float4 aH = make_float4(0.f,0.f,0.f,0.f);
            const int kx0 = kq*16;
            #pragma unroll 4
            for (int k = kx0; k < kx0+16; ++k) {
                float xv = xS[k];
                float4 w = *(const float4*)(wihT + (size_t)k*G3 + r0);
                aI.x += w.x*xv; aI.y += w.y*xv; aI.z += w.z*xv; aI.w += w.w*xv;
            }
            const int kh0 = kq*128;
            #pragma unroll 4
            for (int k = kh0; k < kh0+128; ++k) {
                float hv = hS[k];
                float4 w = *(const float4*)(whhT + (size_t)k*G3 + r0);
                aH.x += w.x*hv; aH.y += w.y*hv; aH.z += w.z*hv; aH.w += w.w*hv;
            }
            pI[kq][c] = aI; pH[kq][c] = aH;
        }
        __syncthreads();
        // reduce over k-quarters + bias + gate staging: thread -> (gate g2, dim d)
        {
            const int g2 = tid >> 7, d = tid & 127;
            const int c2 = g2*32 + (d>>2), e = d & 3;
            float AI = 0.f, AH = 0.f;
            #pragma unroll
            for (int q = 0; q < 4; ++q) {
                float4 vi = pI[q][c2], vh = pH[q][c2];
                AI += (e==0)?vi.x:(e==1)?vi.y:(e==2)?vi.z:vi.w;
                AH += (e==0)?vh.x:(e==1)?vh.y:(e==2)?vh.z:vh.w;
            }
            const int rg = g2*512 + s*128 + d;
            AI += b_ih[rg]; AH += b_hh[rg];
            if (g2 == 0)      grS[d] = AI + AH;
            else if (g2 == 1) gzS[d] = AI + AH;
            else              { giN[d] = AI; ghN[d] = AH; }
        }
        __syncthreads();
        if (tid < 128) {
            const int D = s*128 + tid;
            float rg = sigm(grS[tid]);
            float zg = sigm(gzS[tid]);
            float ng = tanhf(giN[tid] + rg*ghN[tid]);
            float hn = (1.f-zg)*ng + zg*hS[D];
            h_all[((size_t)t*NB + n)*HID + D] = hn;
            __hip_atomic_store(&hG[n*HID + D], hn, __ATOMIC_RELAXED, __HIP_MEMORY_SCOPE_AGENT);
        }
        __syncthreads();   // all slice stores drained (vmcnt 0) before arrival
        if (t+1 < TT) {
            if (tid == 0) {
                __hip_atomic_fetch_add(&flags[n], 1, __ATOMIC_RELEASE, __HIP_MEMORY_SCOPE_AGENT);
                while (__hip_atomic_load(&flags[n], __ATOMIC_ACQUIRE, __HIP_MEMORY_SCOPE_AGENT) < 4*(t+1)) {
                    __builtin_amdgcn_s_sleep(4);
                }
            }
            __syncthreads();
            for (int i = tid; i < 512; i += 384)
                hS[i] = __hip_atomic_load(&hG[n*HID + i], __ATOMIC_RELAXED, __HIP_MEMORY_SCOPE_AGENT);
            // loop-top __syncthreads covers hS visibility
        }
    }
}

// ---------------- xi = relu(h_all) @ Wf^T + bf  (128x64 tiles, 8x4 acc) ----------------
__global__ __launch_bounds__(256) void k_xi(
    const float* __restrict__ h_all,
    const float* __restrict__ Wf,
    const float* __restrict__ bf,
    float* __restrict__ xi_all)
{
    __shared__ float As[16][132];
    __shared__ float Bs[16][68];
    const int jt = blockIdx.x * 64;
    const int it = blockIdx.y * 128;
    const int tid = threadIdx.x;
    const int lc = tid & 15, lr = tid >> 4;
    const int tx = tid & 15, ty = tid >> 4;
    float acc[8][4] = {};

    for (int k0 = 0; k0 < HID; k0 += 16) {
        #pragma unroll
        for (int s = 0; s < 8; ++s) {
            int i = lr*8 + s;
            As[lc][i] = fmaxf(h_all[(size_t)(it + i)*HID + k0 + lc], 0.f);
        }
        #pragma unroll
        for (int s = 0; s < 4; ++s) {
            int j = lr*4 + s;
            Bs[lc][j] = (jt + j < XID) ? Wf[(size_t)(jt + j)*HID + k0 + lc] : 0.f;
        }
        __syncthreads();
        #pragma unroll
        for (int k = 0; k < 16; ++k) {
            float a[8], b[4];
            #pragma unroll
            for (int u = 0; u < 8; ++u) a[u] = As[k][ty*8+u];
            #pragma unroll
            for (int v = 0; v < 4; ++v) b[v] = Bs[k][tx*4+v];
            #pragma unroll
            for (int u = 0; u < 8; ++u)
                #pragma unroll
                for (int v = 0; v < 4; ++v) acc[u][v] += a[u]*b[v];
        }
        __syncthreads();
    }
    #pragma unroll
    for (int u = 0; u < 8; ++u)
        #pragma unroll
        for (int v = 0; v < 4; ++v) {
            int i = it + ty*8 + u, j = jt + tx*4 + v;
            if (j < XID) xi_all[(size_t)i*XID + j] = acc[u][v] + bf[j];
        }
}

// ---------------- critic head ----------------
__global__ __launch_bounds__(64) void k_val(
    const float* __restrict__ h_all, const float* __restrict__ Wc,
    const float* __restrict__ bc, float* __restrict__ out)
{
    const int row = blockIdx.x;
    const int lane = threadIdx.x;
    float acc = 0.f;
    for (int d = lane; d < HID; d += 64) acc += h_all[(size_t)row*HID + d]*Wc[d];
    for (int off = 32; off; off >>= 1) acc += __shfl_down(acc, off);
    if (lane == 0) out[(size_t)row*17 + 16] = acc + bc[0];
}

// ---------------- memory recurrence: 1024 threads, M in registers, L in LDS ----------------
#define LPAD 132
#define SROW 544
#define DYN_FLOATS (128*LPAD + 16*SROW)
// chunked operand layout: column d -> chunk (d>>6), offset (d&63); row stride 68 (bank-spread)
#define CIDX(d) ((((d)>>6)*68) + ((d)&63))

__global__ __launch_bounds__(1024) void k_mem(
    const float* __restrict__ xi_all, // [1024][3607]
    const float* __restrict__ Wa,     // [16][512]
    const float* __restrict__ ba,     // [16]
    float* __restrict__ out)          // [1024][17]
{
    extern __shared__ __align__(16) float dynS[];
    float* Lm  = dynS;                // [128][LPAD]
    float* scr = dynS + 128*LPAD;     // [16][SROW]

    const int n = blockIdx.x;
    const int tid = threadIdx.x;
    const int lane = tid & 63;
    const int wv = tid >> 6;          // 0..15
    const int m8 = tid >> 3;          // row 0..127
    const int q8 = tid & 7;           // col-group 0..7 (64 cols each)

    // chunked-padded operands: conflict-free for the per-q8 float4 reads
    __shared__ __align__(16) float KrC[4*544];            // [head][8 chunks][68]
    __shared__ __align__(16) float kwC[544], eC[544], vC[544];
    __shared__ __align__(16) float wrC[4*136];            // [head][2 chunks][68]
    __shared__ __align__(16) float r_S[512];
    __shared__ float dotK_S[4][132], fwd_S[4][132], bwd_S[4][132];
    __shared__ float u_S[128], ww_S[128], p_S[128], cw_S[128], srt_S[128], aS_S[128];
    __shared__ float Mn2_S[128], dw_S[128];
    __shared__ int   rk_S[128];
    __shared__ float wred[16][6];
    __shared__ float scal_S[8];                 // 0=bw 1=ga 2=gw 3=kwn
    __shared__ float PiRaw[12];
    __shared__ float Pi_S[4][3], Br_S[4], KrN_S[4], F_S[4];
    __shared__ float ba_S[16], logit_S[16];

    // M[m8][q8*64 + 4c + j], c<16 : 16 float4 per thread (64 VGPRs)
    float4 Mreg[16];
    #pragma unroll
    for (int i = 0; i < 16; ++i) Mreg[i] = make_float4(0.f,0.f,0.f,0.f);

    for (int i = tid; i < 128*LPAD; i += 1024) Lm[i] = 0.f;
    if (tid < 16) ba_S[tid] = ba[tid];
    if (tid < 128) { u_S[tid]=0.f; ww_S[tid]=0.f; p_S[tid]=0.f; Mn2_S[tid]=0.f; }
    if (tid < 512) wrC[(tid>>7)*136 + CIDX(tid&127)] = 0.f;

    // Wa resident in registers: wave wv owns logit wv; lane holds d = lane+64j
    float waR[8];
    #pragma unroll
    for (int j = 0; j < 8; ++j) waR[j] = Wa[(wv<<9) + lane + (j<<6)];

    // extra-scalar mapping (23 scalars on threads 1000..1022)
    const bool hasEx = (tid >= 1000 && tid < 1023);
    int exIdx = 0;
    if (tid >= 1000 && tid < 1004)      exIdx = 2048 + (tid - 1000);  // Br
    else if (tid == 1004)               exIdx = 2564;                 // bw
    else if (tid >= 1005 && tid < 1023) exIdx = 3589 + (tid - 1005);  // F(4),ga,gw,Pi(12)

    // initial prefetch (t = 0)
    const float* xi0 = xi_all + (size_t)n*XID;
    float pKrA = xi0[tid];
    float pKrB = xi0[1024 + tid];
    float pkw = 0.f, pv = 0.f, pe = 0.f;
    if (tid < 512) { pkw = xi0[2052 + tid]; pv = xi0[3077 + tid]; }
    else           { pe  = xi0[2565 + (tid - 512)]; }
    float pex = hasEx ? xi0[exIdx] : 0.f;
    __syncthreads();   // b0: LDS init done

    for (int t = 0; t < TT; ++t) {
        float scv = 0.f, ev2 = 0.f;

        // ---- P0: reg -> LDS with activations; norm partials; issue prefetch(t+1) ----
        {
            int d = tid & 511, hh = tid >> 9;
            int co = CIDX(d);
            KrC[hh*544 + co]     = pKrA;
            KrC[(2+hh)*544 + co] = pKrB;
        }
        if (tid < 512) { int co = CIDX(tid); kwC[co] = pkw; vC[co] = pv; }
        else { int s2 = tid - 512; int co = CIDX(s2); eC[co] = sigm(pe); }
        if (hasEx) {
            if (tid < 1004)      Br_S[tid-1000] = splus(pex);
            else if (tid==1004)  scal_S[0] = splus(pex);
            else if (tid < 1009) F_S[tid-1005] = sigm(pex);
            else if (tid==1009)  scal_S[1] = sigm(pex);
            else if (tid==1010)  scal_S[2] = sigm(pex);
            else                 PiRaw[tid-1011] = pex;
        }
        {
            float sA = wsum64(pKrA*pKrA);
            float sB = wsum64(pKrB*pKrB);
            float sK = wsum64(pkw*pkw);
            if (lane == 0) { wred[wv][0]=sA; wred[wv][1]=sB; wred[wv][2]=sK; }
        }
        {   // prefetch next step
            int tn = (t+1 < TT) ? (t+1) : t;
            const float* xin = xi_all + (size_t)(tn*NB + n)*XID;
            pKrA = xin[tid]; pKrB = xin[1024 + tid];
            if (tid < 512) { pkw = xin[2052 + tid]; pv = xin[3077 + tid]; }
            else           { pe  = xin[2565 + (tid - 512)]; }
            if (hasEx) pex = xin[exIdx];
        }
        __syncthreads();   // b1

        // ---- A: finalize norms; usage update (old wr/ww); kw dots on OLD M ----
        if (tid < 4) {
            float s = 0.f;
            #pragma unroll
            for (int w = 0; w < 8; ++w) s += wred[(tid&1)*8 + w][tid>>1];
            KrN_S[tid] = sqrtf(s);
        } else if (tid == 4) {
            float s = 0.f;
            #pragma unroll
            for (int w = 0; w < 8; ++w) s += wred[w][2];
            scal_S[3] = sqrtf(s);
        }
        if (tid < 128) {
            int co = CIDX(tid);
            float psi = (1.f - F_S[0]*wrC[co])      * (1.f - F_S[1]*wrC[136+co])
                      * (1.f - F_S[2]*wrC[272+co])  * (1.f - F_S[3]*wrC[408+co]);
            float uu = u_S[tid], w = ww_S[tid];
            u_S[tid] = (uu + w - uu*w)*psi;
        }
        {
            const float* kwp = kwC + q8*68;
            float dw = 0.f;
            #pragma unroll
            for (int c = 0; c < 16; ++c) {
                float4 x = Mreg[c];
                float4 kk = *(const float4*)(kwp + 4*c);
                dw += x.x*kk.x + x.y*kk.y + x.z*kk.z + x.w*kk.w;
            }
            dw += __shfl_xor(dw,1); dw += __shfl_xor(dw,2); dw += __shfl_xor(dw,4);
            if (q8 == 0) dw_S[m8] = dw;
        }
        __syncthreads();   // b2

        // ---- B: cw scores (old-M norm carried in Mn2_S); parallel rank; cwmax; Pi softmax ----
        {
            float um = u_S[m8];
            int rk = 0;
            #pragma unroll
            for (int jj = 0; jj < 16; ++jj) {
                int j = jj*8 + q8;
                float uj = u_S[j];
                rk += (uj < um || (uj == um && j < m8)) ? 1 : 0;
            }
            rk += __shfl_xor(rk,1); rk += __shfl_xor(rk,2); rk += __shfl_xor(rk,4);
            if (q8 == 0) { rk_S[m8] = rk; srt_S[rk] = um; }
        }
        if (tid < 128) {
            float cwv = scal_S[0]*dw_S[tid]/(Mn2_S[tid]*scal_S[3] + 1e-8f);
            cw_S[tid] = cwv;
            float mx = wmax64(cwv);
            if (lane == 0) wred[wv][0] = mx;
        } else if (tid >= 136 && tid < 140) {
            int h = tid - 136;
            float p0 = PiRaw[3*h], p1 = PiRaw[3*h+1], p2 = PiRaw[3*h+2];
            float mx = fmaxf(p0, fmaxf(p1, p2));
            float e0=__expf(p0-mx), e1=__expf(p1-mx), e2=__expf(p2-mx);
            float s = e0+e1+e2;
            Pi_S[h][0]=e0/s; Pi_S[h][1]=e1/s; Pi_S[h][2]=e2/s;
        }
        __syncthreads();   // b3

        // ---- C: cw exp+sum partials; wave0 does allocation scan ----
        if (tid < 128) {
            float ev = __expf(cw_S[tid] - fmaxf(wred[0][0], wred[1][0]));
            cw_S[tid] = ev;
            float s = wsum64(ev);
            if (lane == 0) wred[wv][1] = s;
        }
        if (wv == 0) {
            float x0 = srt_S[2*lane], x1 = srt_S[2*lane+1];
            float pp = x0*x1;
            float sc = pp;
            #pragma unroll
            for (int off = 1; off < 64; off <<= 1) {
                float y = __shfl_up(sc, off);
                if (lane >= off) sc *= y;
            }
            float excl = __shfl_up(sc, 1);
            if (lane == 0) excl = 1.f;
            aS_S[2*lane]   = (1.f - x0)*excl;
            aS_S[2*lane+1] = (1.f - x1)*excl*x0;
        }
        __syncthreads();   // b4

        // ---- E: write weighting ww + sum partials ----
        if (tid < 128) {
            float cwsum = wred[0][1] + wred[1][1];
            float alloc = aS_S[rk_S[tid]];
            float ga = scal_S[1], gw = scal_S[2];
            float w = gw*(ga*alloc + (1.f-ga)*cw_S[tid]/cwsum);
            ww_S[tid] = w;
            float s = wsum64(w);
            if (lane == 0) wred[wv][0] = s;
        }
        __syncthreads();   // b5

        // ---- G: precedence; M erase/write + read-key dots + new norm ----
        if (tid < 128) {
            float sww = wred[0][0] + wred[1][0];
            p_S[tid] = (1.f - sww)*p_S[tid] + ww_S[tid];
        }
        {
            const int base = q8*68;
            const float* ep  = eC + base;
            const float* vp  = vC + base;
            const float* k0p = KrC + base;
            const float* k1p = KrC + 544 + base;
            const float* k2p = KrC + 1088 + base;
            const float* k3p = KrC + 1632 + base;
            float wwm = ww_S[m8];
            float nrm=0.f, d0=0.f, d1=0.f, d2=0.f, d3=0.f;
            #pragma unroll
            for (int c = 0; c < 16; ++c) {
                float4 x  = Mreg[c];
                float4 ee = *(const float4*)(ep + 4*c);
                float4 vv = *(const float4*)(vp + 4*c);
                x.x = x.x*(1.f - wwm*ee.x) + wwm*vv.x;
                x.y = x.y*(1.f - wwm*ee.y) + wwm*vv.y;
                x.z = x.z*(1.f - wwm*ee.z) + wwm*vv.z;
                x.w = x.w*(1.f - wwm*ee.w) + wwm*vv.w;
                Mreg[c] = x;
                nrm += x.x*x.x + x.y*x.y + x.z*x.z + x.w*x.w;
                float4 k0 = *(const float4*)(k0p + 4*c);
                float4 k1 = *(const float4*)(k1p + 4*c);
                float4 k2 = *(const float4*)(k2p + 4*c);
                float4 k3 = *(const float4*)(k3p + 4*c);
                d0 += x.x*k0.x + x.y*k0.y + x.z*k0.z + x.w*k0.w;
                d1 += x.x*k1.x + x.y*k1.y + x.z*k1.z + x.w*k1.w;
                d2 += x.x*k2.x + x.y*k2.y + x.z*k2.z + x.w*k2.w;
                d3 += x.x*k3.x + x.y*k3.y + x.z*k3.z + x.w*k3.w;
            }
            nrm += __shfl_xor(nrm,1); nrm += __shfl_xor(nrm,2); nrm += __shfl_xor(nrm,4);
            d0  += __shfl_xor(d0,1);  d0  += __shfl_xor(d0,2);  d0  += __shfl_xor(d0,4);
            d1  += __shfl_xor(d1,1);  d1  += __shfl_xor(d1,2);  d1  += __shfl_xor(d1,4);
            d2  += __shfl_xor(d2,1);  d2  += __shfl_xor(d2,2);  d2  += __shfl_xor(d2,4);
            d3  += __shfl_xor(d3,1);  d3  += __shfl_xor(d3,2);  d3  += __shfl_xor(d3,4);
            if (q8 == 4) Mn2_S[m8] = sqrtf(nrm);
            else if (q8 < 4) dotK_S[q8][m8] = (q8==0) ? d0 : ((q8==1) ? d1 : ((q8==2) ? d2 : d3));
        }
        __syncthreads();   // b6

        // ---- H: link matrix update (contiguous 16-row blocks; wr/ww staged as float4) ----
        {
            const int j2 = tid & 127, w8 = tid >> 7;
            float wwj = ww_S[j2], pj = p_S[j2];
            float b0=0.f,b1=0.f,b2=0.f,b3=0.f;
            #pragma unroll
            for (int c2 = 0; c2 < 4; ++c2) {
                const int r0 = (w8<<4) + (c2<<2);
                const int bidx = CIDX(r0);
                float4 wwv = *(const float4*)&ww_S[r0];
                float4 w0v = *(const float4*)&wrC[bidx];
                float4 w1v = *(const float4*)&wrC[136+bidx];
                float4 w2v = *(const float4*)&wrC[272+bidx];
                float4 w3v = *(const float4*)&wrC[408+bidx];
                #pragma unroll
                for (int s4 = 0; s4 < 4; ++s4) {
                    int i2 = r0 + s4;
                    float wwi = (s4==0)?wwv.x:(s4==1)?wwv.y:(s4==2)?wwv.z:wwv.w;
                    float lold = Lm[i2*LPAD + j2];
                    float ln = (1.f - wwi - wwj)*lold + wwi*pj;
                    Lm[i2*LPAD + j2] = ln;
                    b0 += ln*((s4==0)?w0v.x:(s4==1)?w0v.y:(s4==2)?w0v.z:w0v.w);
                    b1 += ln*((s4==0)?w1v.x:(s4==1)?w1v.y:(s4==2)?w1v.z:w1v.w);
                    b2 += ln*((s4==0)?w2v.x:(s4==1)?w2v.y:(s4==2)?w2v.z:w2v.w);
                    b3 += ln*((s4==0)?w3v.x:(s4==1)?w3v.y:(s4==2)?w3v.z:w3v.w);
                }
            }
            float* sp = scr + w8*SROW + j2;
            sp[0]=b0; sp[132]=b1; sp[264]=b2; sp[396]=b3;
        }
        __syncthreads();   // b7

        // ---- I: bwd combine; fwd (LDS rows); content-read scores + max ----
        if (tid < 512) {
            int h = tid>>7, mm = tid&127;
            float s = 0.f;
            #pragma unroll
            for (int g = 0; g < 8; ++g) s += scr[g*SROW + h*132 + mm];
            bwd_S[h][mm] = s;
        }
        {
            const float* Lr = Lm + m8*LPAD + q8*16;
            const int wb = ((q8>>2)*68) + ((q8&3)<<4);
            float f0=0.f,f1=0.f,f2=0.f,f3=0.f;
            #pragma unroll
            for (int c = 0; c < 4; ++c) {
                float4 lv = *(const float4*)(Lr + 4*c);
                float4 w0 = *(const float4*)&wrC[wb + 4*c];
                float4 w1 = *(const float4*)&wrC[136 + wb + 4*c];
                float4 w2 = *(const float4*)&wrC[272 + wb + 4*c];
                float4 w3 = *(const float4*)&wrC[408 + wb + 4*c];
                f0 += lv.x*w0.x + lv.y*w0.y + lv.z*w0.z + lv.w*w0.w;
                f1 += lv.x*w1.x + lv.y*w1.y + lv.z*w1.z + lv.w*w1.w;
                f2 += lv.x*w2.x + lv.y*w2.y + lv.z*w2.z + lv.w*w2.w;
                f3 += lv.x*w3.x + lv.y*w3.y + lv.z*w3.z + lv.w*w3.w;
            }
            f0 += __shfl_xor(f0,1); f0 += __shfl_xor(f0,2); f0 += __shfl_xor(f0,4);
            f1 += __shfl_xor(f1,1); f1 += __shfl_xor(f1,2); f1 += __shfl_xor(f1,4);
            f2 += __shfl_xor(f2,1); f2 += __shfl_xor(f2,2); f2 += __shfl_xor(f2,4);
            f3 += __shfl_xor(f3,1); f3 += __shfl_xor(f3,2); f3 += __shfl_xor(f3,4);
            if (q8 < 4) fwd_S[q8][m8] = (q8==0) ? f0 : ((q8==1) ? f1 : ((q8==2) ? f2 : f3));
        }
        if (tid < 512) {
            int h = tid>>7, mm = tid&127;
            scv = Br_S[h]*dotK_S[h][mm]/(Mn2_S[mm]*KrN_S[h] + 1e-8f);
            float mxv = wmax64(scv);
            if (lane == 0) wred[wv][0] = mxv;
        }
        __syncthreads();   // b8

        // ---- J: content-read exp + sum ----
        if (tid < 512) {
            int h = tid>>7;
            float hmax = fmaxf(wred[2*h][0], wred[2*h+1][0]);
            ev2 = __expf(scv - hmax);
            float s = wsum64(ev2);
            if (lane == 0) wred[wv][1] = s;
        }
        __syncthreads();   // b9

        // ---- K: new read weights ----
        if (tid < 512) {
            int h = tid>>7, mm = tid&127;
            float hsum = wred[2*h][1] + wred[2*h+1][1];
            float cr = ev2/hsum;
            wrC[h*136 + CIDX(mm)] = Pi_S[h][0]*bwd_S[h][mm] + Pi_S[h][1]*cr + Pi_S[h][2]*fwd_S[h][mm];
        }
        __syncthreads();   // b10

        // ---- M: read vectors (permlane32 pair-reduce over rows; one b64 write per chunk) ----
        {
            const int co = CIDX(m8);
            float srtm = wrC[co] + wrC[136+co] + wrC[272+co] + wrC[408+co];
            float* sp = scr + wv*SROW + q8*68 + ((lane>>5)<<1);
            #pragma unroll
            for (int c = 0; c < 16; ++c) {
                float v0 = srtm*Mreg[c].x;
                float v1 = srtm*Mreg[c].y;
                float v2 = srtm*Mreg[c].z;
                float v3 = srtm*Mreg[c].w;
                asm volatile("v_permlane32_swap_b32 %0, %1" : "+v"(v0), "+v"(v2));
                float A = v0 + v2;            // lanes<32: col 4c+0 pair; lanes>=32: col 4c+2 pair
                asm volatile("v_permlane32_swap_b32 %0, %1" : "+v"(v1), "+v"(v3));
                float B = v1 + v3;            // lanes<32: col 4c+1 pair; lanes>=32: col 4c+3 pair
                A += __shfl_xor(A, 8); A += __shfl_xor(A, 16);
                B += __shfl_xor(B, 8); B += __shfl_xor(B, 16);
                if ((lane & 31) < 8) *(float2*)(sp + 4*c) = make_float2(A, B);
            }
        }
        __syncthreads();   // b11

        // ---- N: combine r over 16 waves ----
        if (tid < 512) {
            int off = ((tid>>6)*68) + (tid&63);
            float r = 0.f;
            #pragma unroll
            for (int w = 0; w < 16; ++w) r += scr[w*SROW + off];
            r_S[tid] = r;
        }
        __syncthreads();   // b12

        // ---- O: actor logits (one wave per logit, Wa in registers) ----
        {
            float acc = 0.f;
            #pragma unroll
            for (int j = 0; j < 8; ++j) acc += waR[j]*r_S[lane + (j<<6)];
            acc = wsum64(acc);
            if (lane == 0) logit_S[wv] = acc + ba_S[wv];
        }
        __syncthreads();   // b13

        // ---- P: actor softmax + output (16 lanes) ----
        if (tid < 16) {
            float lg = logit_S[tid];
            float mx = lg;
            mx = fmaxf(mx, __shfl_xor(mx,1)); mx = fmaxf(mx, __shfl_xor(mx,2));
            mx = fmaxf(mx, __shfl_xor(mx,4)); mx = fmaxf(mx, __shfl_xor(mx,8));
            float ex2 = __expf(lg - mx);
            float s = ex2;
            s += __shfl_xor(s,1); s += __shfl_xor(s,2);
            s += __shfl_xor(s,4); s += __shfl_xor(s,8);
            out[(size_t)(t*NB + n)*17 + tid] = ex2/s;
        }
    }
}

// ---------------- host launch ----------------
extern "C" void kernel_launch(void* const* d_in, const int* in_sizes, int n_in,
                              void* d_out, int out_size, void* d_ws, size_t ws_size,
                              hipStream_t stream) {
    const float* inp  = (const float*)d_in[0];
    const float* w_ih = (const float*)d_in[1];
    const float* w_hh = (const float*)d_in[2];
    const float* b_ih = (const float*)d_in[3];
    const float* b_hh = (const float*)d_in[4];
    const float* Wf   = (const float*)d_in[5];
    const float* bf   = (const float*)d_in[6];
    const float* Wa   = (const float*)d_in[7];
    const float* ba   = (const float*)d_in[8];
    const float* Wc   = (const float*)d_in[9];
    const float* bc   = (const float*)d_in[10];
    float* out = (float*)d_out;

    float* ws = (float*)d_ws;
    float* wihT   = ws;                       // 64*1536
    float* whhT   = ws + 98304;               // 512*1536
    float* h_all  = ws + 884736;              // 1024*512
    float* xi_all = ws + 1409024;             // 1024*3607
    float* hG     = ws + 5102592;             // 32*512 h exchange
    int*   flags  = (int*)(ws + 5119008);     // 32 counters

    static int dynset = 0;
    if (!dynset) {
        hipFuncSetAttribute(reinterpret_cast<const void*>(k_mem),
                            hipFuncAttributeMaxDynamicSharedMemorySize,
                            DYN_FLOATS*4);
        dynset = 1;
    }

    hipMemsetAsync(flags, 0, NB*sizeof(int), stream);

    dim3 tb(32, 8);
    k_transpose<<<dim3(48, 2),  tb, 0, stream>>>(w_ih, wihT, G3, DOBS);
    k_transpose<<<dim3(48, 16), tb, 0, stream>>>(w_hh, whhT, G3, HID);
    k_gru<<<NB*4, 384, 0, stream>>>(inp, wihT, whhT, b_ih, b_hh, h_all, hG, flags);
    k_xi<<<dim3(57, 8), 256, 0, stream>>>(h_all, Wf, bf, xi_all);
    k_val<<<TT*NB, 64, 0, stream>>>(h_all, Wc, bc, out);
    k_mem<<<NB, 1024, DYN_FLOATS*4, stream>>>(xi_all, Wa, ba, out);
}